// Round 6
// baseline (396.925 us; speedup 1.0000x reference)
//
#include <hip/hip_runtime.h>
#include <math.h>

#define B_ 16
#define W_ 2048
#define C_ 512

// ---------------- workspace layout (bytes) ----------------
// Xb  (bf16) [B,W,C]  @ 0          (33554432 B)
// Bt  (bf16) [B,C,C]  @ 33554432   ( 8388608 B)   Bt[b][j][i] = relu(adj[b][i][j])/indeg[b][j]
// Xsp (bf16) [B,W,C]  @ 41943040   (33554432 B)
// tt    f32  [B,W]    @ 75497472   (  131072 B)   (raw row sums; 1/C folded at consumer)
#define OFF_XB    0
#define OFF_BT    33554432
#define OFF_XSP   41943040
#define OFF_TT    75497472

typedef short v8s __attribute__((ext_vector_type(8)));
typedef float v4f __attribute__((ext_vector_type(4)));
typedef unsigned int u32;

__device__ __forceinline__ float softplusf(float x) {
    return fmaxf(x, 0.f) + log1pf(expf(-fabsf(x)));
}
__device__ __forceinline__ unsigned short f2bf(float x) {
    unsigned int u = __float_as_uint(x);
    unsigned int r = (u + 0x7FFFu + ((u >> 16) & 1u)) >> 16;   // RNE
    return (unsigned short)r;
}
__device__ __forceinline__ float bf2f(unsigned int h) {
    return __uint_as_float(h << 16);
}
// async global->LDS, 16B per lane; LDS dest must be wave-uniform base + lane*16
__device__ __forceinline__ void gload16(const ushort* g, ushort* l) {
    __builtin_amdgcn_global_load_lds(
        (const __attribute__((address_space(1))) u32*)(g),
        (__attribute__((address_space(3))) u32*)(l), 16, 0, 0);
}
// nontemporal 16B store — must use a native clang vector type, not HIP float4
__device__ __forceinline__ void st_nt4(float* p, float a, float b, float c, float d) {
    v4f v = {a, b, c, d};
    __builtin_nontemporal_store(v, (v4f*)p);
}

// ---- kernel 1: single-pass in-degree + relu/normalize/transpose bf16 ----
// one block per (32-col stripe, batch). Whole stripe staged in LDS (68 KB,
// stride 33 -> max 2-way bank aliasing = free). adj read ONCE from HBM.
// Also zeroes the tt accumulator slice (replaces a memset dispatch).
__global__ __launch_bounds__(512) void prep_adj(const float* __restrict__ adj,
                                                ushort* __restrict__ Bt,
                                                float* __restrict__ tt) {
    __shared__ float stripe[C_][33];
    __shared__ float cs[16][32];
    __shared__ float inv[32];
    const int b = blockIdx.y, j0 = blockIdx.x * 32;
    const int tid = threadIdx.x;
    const int tx = tid & 31, ty = tid >> 5;          // ty 0..15
    const float* src = adj + (size_t)b * C_ * C_ + j0;

    // zero the tt slice for this block (256 blocks x 128 floats = B*W)
    if (tid < 128) tt[(blockIdx.y * 16 + blockIdx.x) * 128 + tid] = 0.f;

    float s = 0.f;
#pragma unroll 8
    for (int it = 0; it < 32; it++) {
        int row = it * 16 + ty;
        float v = fmaxf(src[(size_t)row * C_ + tx], 0.f);
        stripe[row][tx] = v;
        s += v;
    }
    cs[ty][tx] = s;
    __syncthreads();
    if (ty == 0) {
        float tot = 0.f;
#pragma unroll
        for (int r = 0; r < 16; r++) tot += cs[r][tx];
        inv[tx] = 1.f / fmaxf(tot, 1e-4f);
    }
    __syncthreads();

    const int jr = tid >> 4;           // 0..31
    const int ic = (tid & 15) * 2;     // 0..30
    const float iv = inv[jr];
    ushort* dst = Bt + (size_t)b * C_ * C_ + (size_t)(j0 + jr) * C_;
#pragma unroll
    for (int i0t = 0; i0t < C_; i0t += 32) {
        ushort2 o;
        o.x = f2bf(stripe[i0t + ic][jr] * iv);
        o.y = f2bf(stripe[i0t + ic + 1][jr] * iv);
        *(ushort2*)&dst[i0t + ic] = o;
    }
}

// ---- kernel 2: X_sfr fp32 -> bf16 ----
__global__ void convertA(const float* __restrict__ X, ushort* __restrict__ Xb) {
    int idx = blockIdx.x * 256 + threadIdx.x;      // 4 elems per thread
    float4 v = ((const float4*)X)[idx];
    ushort4 o;
    o.x = f2bf(v.x); o.y = f2bf(v.y); o.z = f2bf(v.z); o.w = f2bf(v.w);
    ((ushort4*)Xb)[idx] = o;
}

// ---- kernel 3: MFMA GEMM (m97 structure) + fused tt row-sum epilogue ----
__global__ __launch_bounds__(256) void gemm_mfma(const ushort* __restrict__ Xb,
                                                 const ushort* __restrict__ Bt,
                                                 ushort* __restrict__ Xsp,
                                                 float* __restrict__ tt) {
    __shared__ ushort As[128 * 32];
    __shared__ ushort Bs[128 * 32];
    const int b  = blockIdx.z;
    const int m0 = blockIdx.y * 128;
    const int n0 = blockIdx.x * 128;
    const int tid  = threadIdx.x;
    const int wave = tid >> 6, lane = tid & 63;
    const int quad = lane >> 4, l16 = lane & 15;
    const int mw = (wave & 1) * 64, nw = (wave >> 1) * 64;

    const ushort* Ag = Xb + (size_t)b * W_ * C_ + (size_t)m0 * C_;
    const ushort* Bg = Bt + (size_t)b * C_ * C_ + (size_t)n0 * C_;

    const int sm = tid >> 2;
    const int sk = (tid & 3) * 8;

    v4f acc[4][4];
#pragma unroll
    for (int mt = 0; mt < 4; mt++)
#pragma unroll
        for (int nt = 0; nt < 4; nt++)
            acc[mt][nt] = (v4f){0.f, 0.f, 0.f, 0.f};

    for (int k0 = 0; k0 < C_; k0 += 32) {
        __syncthreads();
        gload16(Ag + (size_t)sm * C_ + k0 + sk,        As + tid * 8);
        gload16(Ag + (size_t)(sm + 64) * C_ + k0 + sk, As + 2048 + tid * 8);
        gload16(Bg + (size_t)sm * C_ + k0 + sk,        Bs + tid * 8);
        gload16(Bg + (size_t)(sm + 64) * C_ + k0 + sk, Bs + 2048 + tid * 8);
        __syncthreads();

        v8s af[4], bf[4];
#pragma unroll
        for (int mt = 0; mt < 4; mt++)
            af[mt] = *(const v8s*)&As[(mw + mt * 16 + l16) * 32 + quad * 8];
#pragma unroll
        for (int nt = 0; nt < 4; nt++)
            bf[nt] = *(const v8s*)&Bs[(nw + nt * 16 + l16) * 32 + quad * 8];
#pragma unroll
        for (int mt = 0; mt < 4; mt++)
#pragma unroll
            for (int nt = 0; nt < 4; nt++)
                acc[mt][nt] = __builtin_amdgcn_mfma_f32_16x16x32_bf16(af[mt], bf[nt], acc[mt][nt], 0, 0, 0);
    }

#pragma unroll
    for (int mt = 0; mt < 4; mt++) {
#pragma unroll
        for (int nt = 0; nt < 4; nt++) {
            int col = n0 + nw + nt * 16 + l16;
#pragma unroll
            for (int r = 0; r < 4; r++) {
                int row = m0 + mw + mt * 16 + quad * 4 + r;
                Xsp[((size_t)b * W_ + row) * C_ + col] = f2bf(acc[mt][nt][r]);
            }
        }
    }

#pragma unroll
    for (int mt = 0; mt < 4; mt++) {
#pragma unroll
        for (int r = 0; r < 4; r++) {
            float s = acc[mt][0][r] + acc[mt][1][r] + acc[mt][2][r] + acc[mt][3][r];
            s += __shfl_xor(s, 1);
            s += __shfl_xor(s, 2);
            s += __shfl_xor(s, 4);
            s += __shfl_xor(s, 8);
            if (l16 == 0) {
                int row = m0 + mw + mt * 16 + quad * 4 + r;
                atomicAdd(&tt[b * W_ + row], s);
            }
        }
    }
}

// ---- kernel 4: fused band-softmax + temporal aggregation + epilogue ----
// 4 rows per wave; union band rows loaded once per wave. Nontemporal output
// stores (201 MB never re-read) keep L2 free for Xsp band reuse.
__global__ __launch_bounds__(256) void final_kernel(const ushort* __restrict__ Xsp,
                                                    const float* __restrict__ tt,
                                                    const float* __restrict__ ltp,
                                                    const float* __restrict__ wqp, const float* __restrict__ bqp,
                                                    const float* __restrict__ wkp, const float* __restrict__ bkp,
                                                    const float* __restrict__ wvp, const float* __restrict__ bvp,
                                                    const float* __restrict__ wmup, const float* __restrict__ bmup,
                                                    const float* __restrict__ wsigp, const float* __restrict__ bsigp,
                                                    const int* __restrict__ k1p, const int* __restrict__ k2p,
                                                    float* __restrict__ out) {
    __shared__ float wlds[4][4][40];   // [wave][row-in-wave][union slot]
    __shared__ float Ssh[4][4];
    const int wid = threadIdx.x >> 6, lane = threadIdx.x & 63;
    const int i0w = blockIdx.x * 16 + wid * 4;    // global row base of this wave
    const int b = i0w >> 11, ib = i0w & (W_ - 1);
    const int K1 = k1p[0], K2 = k2p[0];
    int ns = K2 - K1 + 1;
    if (ns > 16) ns = 16;
    const int n2 = 2 * ns;
    const int nsL = ns + 3;            // union segment length
    const int nu = 2 * nsL;

    for (int k = threadIdx.x; k < 4 * 4 * 40; k += 256) ((float*)wlds)[k] = 0.f;
    __syncthreads();

    if (lane < 32) {
        const float cinv = 1.f / C_;
        const float temp = softplusf(ltp[0]) + 1e-4f;
        const float invt = 1.f / temp;
        const float wkc = wkp[0] * cinv, bk = bkp[0];
        const float wqc = wqp[0] * cinv, bq = bqp[0];
        const float* ttb = tt + b * W_;
        for (int r = 0; r < 4; r++) {
            const int i = ib + r;
            const float q = wqc * ttb[i] + bq;
            int s = lane;
            int j = (s < ns) ? (i - K2 + s) : (i + K1 + (s - ns));
            bool valid = (s < n2) && (j >= 0) && (j < W_);
            float l = valid ? (q * (wkc * ttb[j] + bk) * invt) : -INFINITY;
            float mx = l;
#pragma unroll
            for (int off = 16; off > 0; off >>= 1) mx = fmaxf(mx, __shfl_xor(mx, off, 32));
            float e = valid ? expf(l - mx) : 0.f;
            float T = e;
#pragma unroll
            for (int off = 16; off > 0; off >>= 1) T += __shfl_xor(T, off, 32);
            float p = e / T;
            float S = p;
#pragma unroll
            for (int off = 16; off > 0; off >>= 1) S += __shfl_xor(S, off, 32);
            float rn = 1.f / (S + 1e-6f);
            if (valid) {
                int u = (s < ns) ? (r + s) : (nsL + r + (s - ns));
                wlds[wid][r][u] = p * rn;
            }
            if (lane == 0) Ssh[wid][r] = S * rn;
        }
    }
    __syncthreads();

    const ushort* Xbp = Xsp + (size_t)b * W_ * C_;
    const int c8 = lane * 8;
    float acc[4][8];
#pragma unroll
    for (int r = 0; r < 4; r++)
#pragma unroll
        for (int k = 0; k < 8; k++) acc[r][k] = 0.f;

    for (int u = 0; u < nu; u++) {
        int j = (u < nsL) ? (ib - K2 + u) : (ib + K1 + (u - nsL));
        j = min(max(j, 0), W_ - 1);
        uint4 v = *(const uint4*)(Xbp + (size_t)j * C_ + c8);
        float x[8];
        x[0] = bf2f(v.x & 0xffff); x[1] = bf2f(v.x >> 16);
        x[2] = bf2f(v.y & 0xffff); x[3] = bf2f(v.y >> 16);
        x[4] = bf2f(v.z & 0xffff); x[5] = bf2f(v.z >> 16);
        x[6] = bf2f(v.w & 0xffff); x[7] = bf2f(v.w >> 16);
#pragma unroll
        for (int r = 0; r < 4; r++) {
            float w = wlds[wid][r][u];        // LDS broadcast: wave-uniform
            if (w != 0.f) {                   // divergence-free skip
#pragma unroll
                for (int k = 0; k < 8; k++) acc[r][k] = fmaf(w, x[k], acc[r][k]);
            }
        }
    }

    const float wv = wvp[0], bv = bvp[0];
    const float wmu = wmup[0], bmu = bmup[0];
    const float wsig = wsigp[0], bsig = bsigp[0];
    const size_t N = (size_t)B_ * W_ * C_;

#pragma unroll
    for (int r = 0; r < 4; r++) {
        const float S = Ssh[wid][r];
        uint4 xv = *(const uint4*)(Xbp + (size_t)(ib + r) * C_ + c8);
        float xs[8];
        xs[0] = bf2f(xv.x & 0xffff); xs[1] = bf2f(xv.x >> 16);
        xs[2] = bf2f(xv.y & 0xffff); xs[3] = bf2f(xv.y >> 16);
        xs[4] = bf2f(xv.z & 0xffff); xs[5] = bf2f(xv.z >> 16);
        xs[6] = bf2f(xv.w & 0xffff); xs[7] = bf2f(xv.w >> 16);

        float mu[8], sg[8];
#pragma unroll
        for (int k = 0; k < 8; k++) {
            float xf = fmaf(wv, acc[r][k], bv * S) + xs[k];
            mu[k] = fminf(fmaxf(fmaf(wmu, xf, bmu), -20.f), 20.f);
            sg[k] = softplusf(fmaf(wsig, xf, bsig)) + 0.1f;
        }

        const size_t base = (size_t)(i0w + r) * C_ + c8;
        st_nt4(&out[base],     mu[0], mu[1], mu[2], mu[3]);
        st_nt4(&out[base + 4], mu[4], mu[5], mu[6], mu[7]);
        st_nt4(&out[N + base],     sg[0], sg[1], sg[2], sg[3]);
        st_nt4(&out[N + base + 4], sg[4], sg[5], sg[6], sg[7]);
        st_nt4(&out[2 * N + base],     S, S, S, S);
        st_nt4(&out[2 * N + base + 4], S, S, S, S);
    }
}

extern "C" void kernel_launch(void* const* d_in, const int* in_sizes, int n_in,
                              void* d_out, int out_size, void* d_ws, size_t ws_size,
                              hipStream_t stream) {
    const float* X_sfr = (const float*)d_in[0];
    const float* adj   = (const float*)d_in[1];
    const float* ltp   = (const float*)d_in[2];
    const float* wq    = (const float*)d_in[3];
    const float* bq    = (const float*)d_in[4];
    const float* wk    = (const float*)d_in[5];
    const float* bk    = (const float*)d_in[6];
    const float* wv    = (const float*)d_in[7];
    const float* bv    = (const float*)d_in[8];
    const float* wmu   = (const float*)d_in[9];
    const float* bmu   = (const float*)d_in[10];
    const float* wsig  = (const float*)d_in[11];
    const float* bsig  = (const float*)d_in[12];
    const int*   k1p   = (const int*)d_in[13];
    const int*   k2p   = (const int*)d_in[14];

    char* ws = (char*)d_ws;
    ushort* Xb  = (ushort*)(ws + OFF_XB);
    ushort* Bt  = (ushort*)(ws + OFF_BT);
    ushort* Xsp = (ushort*)(ws + OFF_XSP);
    float*  tt  = (float*)(ws + OFF_TT);
    float*  out = (float*)d_out;

    prep_adj<<<dim3(C_ / 32, B_), 512, 0, stream>>>(adj, Bt, tt);

    convertA<<<(B_ * W_ * C_ / 4) / 256, 256, 0, stream>>>(X_sfr, Xb);

    gemm_mfma<<<dim3(C_ / 128, W_ / 128, B_), 256, 0, stream>>>(Xb, Bt, Xsp, tt);

    final_kernel<<<(B_ * W_) / 16, 256, 0, stream>>>(Xsp, tt, ltp, wq, bq, wk, bk,
                                                     wv, bv, wmu, bmu, wsig, bsig,
                                                     k1p, k2p, out);
}